// Round 8
// baseline (410.779 us; speedup 1.0000x reference)
//
#include <hip/hip_runtime.h>
#include <math.h>

// Problem constants (fixed by the reference):
#define NEXP 4               // n
#define STREAM 4096          // N*C
#define NOUT 24              // n*n + 2n
#define NTOK 16384           // B*L
#define SK_ITERS 20

// Tiling:
#define T_PER_BLOCK 8        // tokens per block (phi reuse factor)
#define WAVES 8              // 512 threads; wave w owns token w, cols 3w..3w+2
#define CHUNK 512            // k-values staged per chunk
#define NCHUNK (STREAM / CHUNK)   // 8

// ---------------------------------------------------------------------------
// Kernel A: phiT[j][k] = scale[k] * phi[k][j]   (24 x 4096, transposed+scaled)
// ---------------------------------------------------------------------------
__global__ __launch_bounds__(256) void k_transpose_scale(
    const float* __restrict__ phi, const float* __restrict__ scale,
    float* __restrict__ phiT) {
  int flat = blockIdx.x * 256 + threadIdx.x;   // 0..98303, flat = k*24 + j
  int k = flat / NOUT;
  int j = flat - k * NOUT;
  phiT[j * STREAM + k] = phi[flat] * scale[k];
}

// ---------------------------------------------------------------------------
// HBM -> LDS direct DMA, 16 B per lane. No VGPR round-trip; counts in vmcnt.
// vmcnt retires IN ORDER: p-loads are issued BEFORE the DMAs each chunk so
// waiting on p never drains the in-flight DMAs.
// ---------------------------------------------------------------------------
typedef const void __attribute__((address_space(1)))* gas_ptr;
typedef void __attribute__((address_space(3)))* las_ptr;
__device__ __forceinline__ void gl_lds16(const float* g, float* s) {
  __builtin_amdgcn_global_load_lds((gas_ptr)g, (las_ptr)s, 16, 0, 0);
}

// Wave w stages its own token's chunk `ch`: 2 DMA loads of 1 KB.
__device__ __forceinline__ void stage_issue(
    int ch, int w, int lane, const float* xw, float* buf) {
  const float* g = xw + ch * CHUNK;
  float* d = buf + w * CHUNK;
  gl_lds16(g + 4 * lane,       d + 4 * lane);
  gl_lds16(g + 256 + 4 * lane, d + 256 + 4 * lane);
}

// ---------------------------------------------------------------------------
// Fused kernel: RMSNorm-dot + heads + Sinkhorn, m stays in LDS.
//   512 threads = 8 waves; 8 tokens/block. Wave w: stages token w (DMA,
//   double-buffered, one barrier/chunk), computes cols 3w..3w+2 for all 8
//   tokens. 24 acc + 24 p VGPRs -> high occupancy (the R3-R7 structure was
//   stuck at 21% occupancy = exposed latency; this is the occupancy fix).
// ---------------------------------------------------------------------------
__global__ __launch_bounds__(512) void k_fused(
    const float* __restrict__ x, const float* __restrict__ phiT,
    const float* __restrict__ bias,
    const float* __restrict__ a_pre_p, const float* __restrict__ a_post_p,
    const float* __restrict__ a_res_p, float* __restrict__ out) {
  __shared__ float lds_x0[T_PER_BLOCK * CHUNK];   // 16 KB
  __shared__ float lds_x1[T_PER_BLOCK * CHUNK];   // 16 KB (double buffer)
  __shared__ float lds_m[T_PER_BLOCK * NOUT];     // 192 floats
  __shared__ float lds_inv[T_PER_BLOCK];          // 1/rms per token

  const int tid  = threadIdx.x;
  const int w    = tid >> 6;       // 0..7
  const int lane = tid & 63;
  const int tok0 = blockIdx.x * T_PER_BLOCK;

  const float4* phiT4 = (const float4*)phiT;
  const float* xw = x + (size_t)(tok0 + w) * STREAM;   // this wave's token

  float acc[T_PER_BLOCK][3];
#pragma unroll
  for (int t = 0; t < T_PER_BLOCK; t++)
#pragma unroll
    for (int jj = 0; jj < 3; jj++) acc[t][jj] = 0.0f;
  float ssq = 0.0f;

  // prologue: issue DMA for chunk 0 into buffer 0 (drained by first barrier)
  stage_issue(0, w, lane, xw, lds_x0);

  for (int ch = 0; ch < NCHUNK; ch++) {
    const float* bufC = (ch & 1) ? lds_x1 : lds_x0;
    float*       bufN = (ch & 1) ? lds_x0 : lds_x1;
    __syncthreads();   // vmcnt(0): chunk-ch DMA landed; prev chunk reads done

    // ---- phiT loads FIRST (retire ahead of the DMAs issued below) ----
    const int pbase = (3 * w) * (STREAM / 4) + ch * (CHUNK / 4);
    float4 p0[3], p1[3];
#pragma unroll
    for (int jj = 0; jj < 3; jj++)
      p0[jj] = phiT4[pbase + jj * (STREAM / 4) + lane];
#pragma unroll
    for (int jj = 0; jj < 3; jj++)
      p1[jj] = phiT4[pbase + jj * (STREAM / 4) + 64 + lane];
    __builtin_amdgcn_sched_barrier(0);   // pin: p-loads before DMA issue

    if (ch + 1 < NCHUNK)
      stage_issue(ch + 1, w, lane, xw, bufN);   // in flight during compute
    __builtin_amdgcn_sched_barrier(0);   // pin: DMA issue before compute body

    // ---- compute: 3 phi columns (j = 3w+jj) x 8 tokens ----
    const float4* l4 = (const float4*)bufC;
#pragma unroll
    for (int i = 0; i < 2; i++) {
      int k4 = i * 64 + lane;
      {
        float4 vo = l4[w * (CHUNK / 4) + k4];   // own token: sumsq
        ssq += vo.x * vo.x + vo.y * vo.y + vo.z * vo.z + vo.w * vo.w;
      }
#pragma unroll
      for (int t = 0; t < T_PER_BLOCK; t++) {
        float4 xv = l4[t * (CHUNK / 4) + k4];
#pragma unroll
        for (int jj = 0; jj < 3; jj++) {
          float4 p = (i == 0) ? p0[jj] : p1[jj];
          float a = acc[t][jj];
          a = fmaf(xv.x, p.x, a);
          a = fmaf(xv.y, p.y, a);
          a = fmaf(xv.z, p.z, a);
          a = fmaf(xv.w, p.w, a);
          acc[t][jj] = a;
        }
      }
    }
  }

  // ---- wave-reduce sumsq (own token w) ----
#pragma unroll
  for (int d = 1; d < 64; d <<= 1) ssq += __shfl_xor(ssq, d, 64);
  if (lane == 0)
    lds_inv[w] = 1.0f / sqrtf(ssq * (1.0f / STREAM) + 1e-20f);

  // ---- wave-reduce the 24 accumulators (butterfly; all lanes get totals) --
#pragma unroll
  for (int d = 1; d < 64; d <<= 1) {
#pragma unroll
    for (int t = 0; t < T_PER_BLOCK; t++)
#pragma unroll
      for (int jj = 0; jj < 3; jj++)
        acc[t][jj] += __shfl_xor(acc[t][jj], d, 64);
  }
  __syncthreads();   // lds_inv visible to all waves

  // ---- write m into LDS: lane t*3+jj holds token t, column j=3w+jj ----
#pragma unroll
  for (int t = 0; t < T_PER_BLOCK; t++) {
    float inv = lds_inv[t];
#pragma unroll
    for (int jj = 0; jj < 3; jj++) {
      if (lane == t * 3 + jj) {
        int j = 3 * w + jj;
        lds_m[t * NOUT + j] = acc[t][jj] * inv + bias[j];
      }
    }
  }
  __syncthreads();   // lds_m visible

  // ---- heads + Sinkhorn tail: 16 lanes per token, first 2 waves only ----
  if (tid < T_PER_BLOCK * 16) {
    int t = tid >> 4;
    int e = tid & 15;            // r*4 + c
    int tok = tok0 + t;

    const float a_res  = *a_res_p;
    const float a_pre  = *a_pre_p;
    const float a_post = *a_post_p;

    float M = expf(a_res * lds_m[t * NOUT + 2 * NEXP + e]);
#pragma unroll 1
    for (int it = 0; it < SK_ITERS; it++) {
      float rs = M + __shfl_xor(M, 1, 64);
      rs += __shfl_xor(rs, 2, 64);
      M = M / (rs + 1e-12f);
      float cs = M + __shfl_xor(M, 4, 64);
      cs += __shfl_xor(cs, 8, 64);
      M = M / (cs + 1e-12f);
    }
    out[2 * NTOK * NEXP + tok * 16 + e] = M;   // h_res at offset 131072

    if (e < NEXP) {
      float z = a_pre * lds_m[t * NOUT + e];
      out[tok * NEXP + e] = 1.0f / (1.0f + expf(-z));
    } else if (e < 2 * NEXP) {
      int j = e - NEXP;
      float z = a_post * lds_m[t * NOUT + NEXP + j];
      out[NTOK * NEXP + tok * NEXP + j] = 2.0f / (1.0f + expf(-z));
    }
  }
}

// ---------------------------------------------------------------------------
extern "C" void kernel_launch(void* const* d_in, const int* in_sizes, int n_in,
                              void* d_out, int out_size, void* d_ws, size_t ws_size,
                              hipStream_t stream) {
  const float* x      = (const float*)d_in[0];
  const float* scale  = (const float*)d_in[1];
  const float* phi    = (const float*)d_in[2];
  const float* bias   = (const float*)d_in[3];
  const float* a_pre  = (const float*)d_in[4];
  const float* a_post = (const float*)d_in[5];
  const float* a_res  = (const float*)d_in[6];
  float* out = (float*)d_out;

  float* phiT = (float*)d_ws;   // 24*4096 = 98304 floats

  k_transpose_scale<<<(NOUT * STREAM) / 256, 256, 0, stream>>>(phi, scale, phiT);
  k_fused<<<NTOK / T_PER_BLOCK, 512, 0, stream>>>(x, phiT, bias, a_pre, a_post,
                                                  a_res, out);
}